// Round 6
// baseline (528.121 us; speedup 1.0000x reference)
//
#include <hip/hip_runtime.h>

#define DIM 192
#define PLANE (DIM * DIM)              // 36864 floats per x-plane
#define VOL (PLANE * DIM)              // 7077888 floats per field (fits int)
#define DCH 12                         // i-chunk depth
#define NCH (DIM / DCH)                // 16 chunks
#define GT 36                          // g-tiles per plane: 9216 float4 / 256
#define NBLK (GT * NCH * 2)            // 1152 blocks

__device__ __forceinline__ float robustf(float x) {
    // branchless Huber: r = m*(|x| - 0.5*m), m = min(|x|, delta); delta = 0.01
    float ax = fabsf(x);
    float m = fminf(ax, 0.01f);
    return m * (ax - 0.5f * m);
}

__device__ __forceinline__ float4 ldg4(const float* __restrict__ p, int off) {
    return *(const float4*)(p + off);
}

__device__ __forceinline__ float4 sub_scale(float4 a, float4 b, float s) {
    return make_float4((a.x - b.x) * s, (a.y - b.y) * s,
                       (a.z - b.z) * s, (a.w - b.w) * s);
}

__device__ __forceinline__ float voxel_loss(
    float du_dx, float du_dy, float du_dz,
    float dv_dx, float dv_dy, float dv_dz,
    float dw_dx, float dw_dy, float dw_dz) {
    const float E_xy = 0.5f * (du_dy + dv_dx);
    const float E_xz = 0.5f * (du_dz + dw_dx);
    const float E_yz = 0.5f * (dv_dz + dw_dy);
    const float tr   = du_dx + dv_dy + dw_dz;

    const float rtr = robustf(tr);
    const float rxx = robustf(du_dx), ryy = robustf(dv_dy), rzz = robustf(dw_dz);
    const float rxy = robustf(E_xy),  rxz = robustf(E_xz),  ryz = robustf(E_yz);

    const float energy = 0.5f * rtr * rtr
                       + 0.5f * (rxx * rxx + ryy * ryy + rzz * rzz
                                 + 2.0f * (rxy * rxy + rxz * rxz + ryz * ryz));

    // Replicate the reference expression EXACTLY (not the true determinant).
    const float jac =
          (1.0f + du_dx) * ((1.0f + dv_dy) * (1.0f + dw_dz) - dv_dz * dw_dy)
        - du_dy * (dv_dx * (1.0f + dw_dz) - dv_dz * (1.0f + dw_dx))
        + du_dz * (dv_dx * dw_dy - (1.0f + dv_dy) * (1.0f + dw_dx));

    return energy + 0.1f * fmaxf(-jac, 0.0f);
}

__device__ __forceinline__ float4 zgrad(float4 c, float lf, float rt,
                                        bool leftEdge, bool rightEdge) {
    float4 g;
    g.x = leftEdge  ? (c.y - c.x) : 0.5f * (c.y - lf);
    g.y = 0.5f * (c.z - c.x);
    g.z = 0.5f * (c.w - c.y);
    g.w = rightEdge ? (c.w - c.z) : 0.5f * (rt - c.z);
    return g;
}

// Flattened (j,k): all 64 lanes carry a float4. Software-pipelined i-march:
// iteration ii+1's 9 float4 loads (+halo) are issued before iteration ii's
// compute; full unroll lets the compiler rename the rotation registers.
__global__ __launch_bounds__(256, 4)
void elastic_main(const float* __restrict__ df, double* __restrict__ partial) {
    const int tid  = threadIdx.x;              // 0..255
    const int lane = tid & 63;
    const int g    = blockIdx.x * 256 + tid;   // float4 index in plane, 0..9215
    const int g4   = g * 4;                    // float offset in plane
    const int gmod = g % 48;                   // float4 index within row
    const int j    = g / 48;
    const int i0   = blockIdx.y * DCH;
    const int b    = blockIdx.z;

    const float* __restrict__ u = df + (size_t)(b * 3 + 0) * VOL;
    const float* __restrict__ v = df + (size_t)(b * 3 + 1) * VOL;
    const float* __restrict__ w = df + (size_t)(b * 3 + 2) * VOL;

    const bool leftEdge  = (gmod == 0);
    const bool rightEdge = (gmod == 47);

    const int jp = (j < DIM - 1) ? j + 1 : j;
    const int jm = (j > 0) ? j - 1 : j;
    const float sy = ((jp - jm) == 2) ? 0.5f : 1.0f;
    const int yOfsP = jp * DIM + gmod * 4;     // float offset within plane
    const int yOfsM = jm * DIM + gmod * 4;

    // z-halo: lane0 needs element g4-1 (its lf), lane63 needs g4+4 (its rt)
    const bool doHalo = (lane == 0) || (lane == 63);
    const int hOfs = (lane == 0) ? (leftEdge ? g4 : g4 - 1)
                                 : (rightEdge ? g4 : g4 + 4);

    // rotation registers: center rows of planes max(i-1,0), i
    float4 um, vm, wm, uc, vc, wc;
    {
        const int im1 = (i0 > 0) ? i0 - 1 : 0;
        um = ldg4(u, im1 * PLANE + g4); vm = ldg4(v, im1 * PLANE + g4);
        wm = ldg4(w, im1 * PLANE + g4);
        uc = ldg4(u, i0 * PLANE + g4);  vc = ldg4(v, i0 * PLANE + g4);
        wc = ldg4(w, i0 * PLANE + g4);
    }

    int oC = i0 * PLANE;                       // plane-i base (float offset)

    // prefetch iteration 0
    float4 up, vp, wp, uyp, uym, vyp, vym, wyp, wym;
    float hu = 0.f, hv = 0.f, hw = 0.f;
    {
        const int oP = oC + ((i0 < DIM - 1) ? PLANE : 0);
        up  = ldg4(u, oP + g4);  vp  = ldg4(v, oP + g4);  wp = ldg4(w, oP + g4);
        uyp = ldg4(u, oC + yOfsP); uym = ldg4(u, oC + yOfsM);
        vyp = ldg4(v, oC + yOfsP); vym = ldg4(v, oC + yOfsM);
        wyp = ldg4(w, oC + yOfsP); wym = ldg4(w, oC + yOfsM);
        if (doHalo) { hu = u[oC + hOfs]; hv = v[oC + hOfs]; hw = w[oC + hOfs]; }
    }

    float vsum = 0.0f;

    #pragma unroll
    for (int ii = 0; ii < DCH; ++ii) {
        const int i = i0 + ii;
        const float sx = (i > 0 && i < DIM - 1) ? 0.5f : 1.0f;

        // stash current iteration's prefetched data (renamed, not copied)
        const float4 cup = up,  cvp = vp,  cwp = wp;
        const float4 cuyp = uyp, cuym = uym;
        const float4 cvyp = vyp, cvym = vym;
        const float4 cwyp = wyp, cwym = wym;
        const float chu = hu, chv = hv, chw = hw;

        // issue next iteration's loads NOW (hidden under this iter's compute)
        if (ii + 1 < DCH) {
            const int oCn = oC + PLANE;
            const int oPn = oCn + ((i + 1 < DIM - 1) ? PLANE : 0);
            up  = ldg4(u, oPn + g4);  vp  = ldg4(v, oPn + g4);
            wp  = ldg4(w, oPn + g4);
            uyp = ldg4(u, oCn + yOfsP); uym = ldg4(u, oCn + yOfsM);
            vyp = ldg4(v, oCn + yOfsP); vym = ldg4(v, oCn + yOfsM);
            wyp = ldg4(w, oCn + yOfsP); wym = ldg4(w, oCn + yOfsM);
            if (doHalo) {
                hu = u[oCn + hOfs]; hv = v[oCn + hOfs]; hw = w[oCn + hOfs];
            }
        }

        // z-neighbor exchange (uc was loaded 2 iterations ago — wait is short)
        float ulf = __shfl_up(uc.w, 1);
        float vlf = __shfl_up(vc.w, 1);
        float wlf = __shfl_up(wc.w, 1);
        float urt = __shfl_down(uc.x, 1);
        float vrt = __shfl_down(vc.x, 1);
        float wrt = __shfl_down(wc.x, 1);
        if (lane == 0)  { ulf = chu; vlf = chv; wlf = chw; }
        if (lane == 63) { urt = chu; vrt = chv; wrt = chw; }

        const float4 du_dz = zgrad(uc, ulf, urt, leftEdge, rightEdge);
        const float4 dv_dz = zgrad(vc, vlf, vrt, leftEdge, rightEdge);
        const float4 dw_dz = zgrad(wc, wlf, wrt, leftEdge, rightEdge);

        const float4 du_dx = sub_scale(cup, um, sx);
        const float4 dv_dx = sub_scale(cvp, vm, sx);
        const float4 dw_dx = sub_scale(cwp, wm, sx);
        const float4 du_dy = sub_scale(cuyp, cuym, sy);
        const float4 dv_dy = sub_scale(cvyp, cvym, sy);
        const float4 dw_dy = sub_scale(cwyp, cwym, sy);

        vsum += voxel_loss(du_dx.x, du_dy.x, du_dz.x,
                           dv_dx.x, dv_dy.x, dv_dz.x,
                           dw_dx.x, dw_dy.x, dw_dz.x);
        vsum += voxel_loss(du_dx.y, du_dy.y, du_dz.y,
                           dv_dx.y, dv_dy.y, dv_dz.y,
                           dw_dx.y, dw_dy.y, dw_dz.y);
        vsum += voxel_loss(du_dx.z, du_dy.z, du_dz.z,
                           dv_dx.z, dv_dy.z, dv_dz.z,
                           dw_dx.z, dw_dy.z, dw_dz.z);
        vsum += voxel_loss(du_dx.w, du_dy.w, du_dz.w,
                           dv_dx.w, dv_dy.w, dv_dz.w,
                           dw_dx.w, dw_dy.w, dw_dz.w);

        // rotate planes
        um = uc; vm = vc; wm = wc;
        uc = cup; vc = cvp; wc = cwp;
        oC += PLANE;
    }

    #pragma unroll
    for (int off = 32; off > 0; off >>= 1)
        vsum += __shfl_down(vsum, off, 64);

    __shared__ float wpart[4];
    if (lane == 0) wpart[tid >> 6] = vsum;
    __syncthreads();
    if (tid == 0) {
        const int blk = blockIdx.x + GT * (blockIdx.y + NCH * blockIdx.z);
        partial[blk] = (double)wpart[0] + (double)wpart[1]
                     + (double)wpart[2] + (double)wpart[3];
    }
}

__global__ __launch_bounds__(256)
void elastic_finalize(const double* __restrict__ partial, float* __restrict__ out) {
    const int t = threadIdx.x;
    double s = 0.0;
    for (int idx = t; idx < NBLK; idx += 256) s += partial[idx];

    #pragma unroll
    for (int off = 32; off > 0; off >>= 1)
        s += __shfl_down(s, off, 64);

    __shared__ double wpart[4];
    if ((t & 63) == 0) wpart[t >> 6] = s;
    __syncthreads();
    if (t == 0) {
        double tot = wpart[0] + wpart[1] + wpart[2] + wpart[3];
        out[0] = (float)(tot * (1.0 / 14155776.0));
    }
}

extern "C" void kernel_launch(void* const* d_in, const int* in_sizes, int n_in,
                              void* d_out, int out_size, void* d_ws, size_t ws_size,
                              hipStream_t stream) {
    const float* df = (const float*)d_in[0];
    double* partial = (double*)d_ws;   // NBLK doubles, plain stores (no init)
    float* out = (float*)d_out;

    dim3 grid(GT, NCH, 2);             // 1152 blocks ≈ 4.5/CU, 16-18 waves/CU
    elastic_main<<<grid, 256, 0, stream>>>(df, partial);
    elastic_finalize<<<1, 256, 0, stream>>>(partial, out);
}

// Round 7
// 244.735 us; speedup vs baseline: 2.1579x; 2.1579x over previous
//
#include <hip/hip_runtime.h>

#define DIM 192
#define PLANE (DIM * DIM)              // 36864 floats per x-plane
#define VOL (PLANE * DIM)              // 7077888 floats per field (fits int)
#define DCH 6                          // i-chunk depth
#define NCH (DIM / DCH)                // 32 chunks
#define GT 36                          // g-tiles per plane: 9216 float4 / 256
#define NBLK (GT * NCH * 2)            // 2304 blocks = 9 blocks/CU

__device__ __forceinline__ float robustf(float x) {
    // branchless Huber: r = m*(|x| - 0.5*m), m = min(|x|, delta); delta = 0.01
    float ax = fabsf(x);
    float m = fminf(ax, 0.01f);
    return m * (ax - 0.5f * m);
}

__device__ __forceinline__ float4 ldg4(const float* __restrict__ p, int off) {
    return *(const float4*)(p + off);
}

__device__ __forceinline__ float4 sub_scale(float4 a, float4 b, float s) {
    return make_float4((a.x - b.x) * s, (a.y - b.y) * s,
                       (a.z - b.z) * s, (a.w - b.w) * s);
}

__device__ __forceinline__ float voxel_loss(
    float du_dx, float du_dy, float du_dz,
    float dv_dx, float dv_dy, float dv_dz,
    float dw_dx, float dw_dy, float dw_dz) {
    const float E_xy = 0.5f * (du_dy + dv_dx);
    const float E_xz = 0.5f * (du_dz + dw_dx);
    const float E_yz = 0.5f * (dv_dz + dw_dy);
    const float tr   = du_dx + dv_dy + dw_dz;

    const float rtr = robustf(tr);
    const float rxx = robustf(du_dx), ryy = robustf(dv_dy), rzz = robustf(dw_dz);
    const float rxy = robustf(E_xy),  rxz = robustf(E_xz),  ryz = robustf(E_yz);

    const float energy = 0.5f * rtr * rtr
                       + 0.5f * (rxx * rxx + ryy * ryy + rzz * rzz
                                 + 2.0f * (rxy * rxy + rxz * rxz + ryz * ryz));

    // Replicate the reference expression EXACTLY (not the true determinant).
    const float jac =
          (1.0f + du_dx) * ((1.0f + dv_dy) * (1.0f + dw_dz) - dv_dz * dw_dy)
        - du_dy * (dv_dx * (1.0f + dw_dz) - dv_dz * (1.0f + dw_dx))
        + du_dz * (dv_dx * dw_dy - (1.0f + dv_dy) * (1.0f + dw_dx));

    return energy + 0.1f * fmaxf(-jac, 0.0f);
}

__device__ __forceinline__ float4 zgrad(float4 c, float lf, float rt,
                                        bool leftEdge, bool rightEdge) {
    float4 g;
    g.x = leftEdge  ? (c.y - c.x) : 0.5f * (c.y - lf);
    g.y = 0.5f * (c.z - c.x);
    g.z = 0.5f * (c.w - c.y);
    g.w = rightEdge ? (c.w - c.z) : 0.5f * (rt - c.z);
    return g;
}

// R5 structure (rolled loop, no explicit prefetch — R6's pipelined full
// unroll spilled: WRITE_SIZE 522 MB of scratch). Latency hiding comes from
// occupancy instead: 64 VGPR -> 8 resident blocks/CU, grid 9 blocks/CU.
__global__ __launch_bounds__(256, 4)
void elastic_main(const float* __restrict__ df, double* __restrict__ partial) {
    const int tid  = threadIdx.x;              // 0..255
    const int lane = tid & 63;
    const int g    = blockIdx.x * 256 + tid;   // float4 index in plane, 0..9215
    const int g4   = g * 4;                    // float offset in plane
    const int gmod = g % 48;                   // float4 index within row
    const int j    = g / 48;
    const int i0   = blockIdx.y * DCH;
    const int b    = blockIdx.z;

    const float* __restrict__ u = df + (size_t)(b * 3 + 0) * VOL;
    const float* __restrict__ v = df + (size_t)(b * 3 + 1) * VOL;
    const float* __restrict__ w = df + (size_t)(b * 3 + 2) * VOL;

    const bool leftEdge  = (gmod == 0);
    const bool rightEdge = (gmod == 47);

    const int jp = (j < DIM - 1) ? j + 1 : j;
    const int jm = (j > 0) ? j - 1 : j;
    const float sy = ((jp - jm) == 2) ? 0.5f : 1.0f;
    const int yOfsP = jp * DIM + gmod * 4;     // float offset within plane
    const int yOfsM = jm * DIM + gmod * 4;

    // z-halo: lane0 needs element g4-1 (its lf), lane63 needs g4+4 (its rt)
    const bool doHalo = (lane == 0) || (lane == 63);
    const int hOfs = (lane == 0) ? (leftEdge ? g4 : g4 - 1)
                                 : (rightEdge ? g4 : g4 + 4);

    // rotation registers: center rows of planes max(i-1,0), i
    float4 um, vm, wm, uc, vc, wc;
    {
        const int im1 = (i0 > 0) ? i0 - 1 : 0;
        um = ldg4(u, im1 * PLANE + g4); vm = ldg4(v, im1 * PLANE + g4);
        wm = ldg4(w, im1 * PLANE + g4);
        uc = ldg4(u, i0 * PLANE + g4);  vc = ldg4(v, i0 * PLANE + g4);
        wc = ldg4(w, i0 * PLANE + g4);
    }

    float vsum = 0.0f;
    int oC = i0 * PLANE;                       // plane-i base (float offset)

    for (int ii = 0; ii < DCH; ++ii) {
        const int i = i0 + ii;
        const int oP = oC + ((i < DIM - 1) ? PLANE : 0);   // clamped i+1 plane
        const float sx = (i > 0 && i < DIM - 1) ? 0.5f : 1.0f;

        const float4 up  = ldg4(u, oP + g4);
        const float4 vp  = ldg4(v, oP + g4);
        const float4 wp  = ldg4(w, oP + g4);
        const float4 uyp = ldg4(u, oC + yOfsP);
        const float4 uym = ldg4(u, oC + yOfsM);
        const float4 vyp = ldg4(v, oC + yOfsP);
        const float4 vym = ldg4(v, oC + yOfsM);
        const float4 wyp = ldg4(w, oC + yOfsP);
        const float4 wym = ldg4(w, oC + yOfsM);

        float hu = 0.f, hv = 0.f, hw = 0.f;
        if (doHalo) {                           // 1 predicated dword load/field
            hu = u[oC + hOfs]; hv = v[oC + hOfs]; hw = w[oC + hOfs];
        }

        float ulf = __shfl_up(uc.w, 1);
        float vlf = __shfl_up(vc.w, 1);
        float wlf = __shfl_up(wc.w, 1);
        float urt = __shfl_down(uc.x, 1);
        float vrt = __shfl_down(vc.x, 1);
        float wrt = __shfl_down(wc.x, 1);
        if (lane == 0)  { ulf = hu; vlf = hv; wlf = hw; }
        if (lane == 63) { urt = hu; vrt = hv; wrt = hw; }

        const float4 du_dz = zgrad(uc, ulf, urt, leftEdge, rightEdge);
        const float4 dv_dz = zgrad(vc, vlf, vrt, leftEdge, rightEdge);
        const float4 dw_dz = zgrad(wc, wlf, wrt, leftEdge, rightEdge);

        const float4 du_dx = sub_scale(up, um, sx);
        const float4 dv_dx = sub_scale(vp, vm, sx);
        const float4 dw_dx = sub_scale(wp, wm, sx);
        const float4 du_dy = sub_scale(uyp, uym, sy);
        const float4 dv_dy = sub_scale(vyp, vym, sy);
        const float4 dw_dy = sub_scale(wyp, wym, sy);

        vsum += voxel_loss(du_dx.x, du_dy.x, du_dz.x,
                           dv_dx.x, dv_dy.x, dv_dz.x,
                           dw_dx.x, dw_dy.x, dw_dz.x);
        vsum += voxel_loss(du_dx.y, du_dy.y, du_dz.y,
                           dv_dx.y, dv_dy.y, dv_dz.y,
                           dw_dx.y, dw_dy.y, dw_dz.y);
        vsum += voxel_loss(du_dx.z, du_dy.z, du_dz.z,
                           dv_dx.z, dv_dy.z, dv_dz.z,
                           dw_dx.z, dw_dy.z, dw_dz.z);
        vsum += voxel_loss(du_dx.w, du_dy.w, du_dz.w,
                           dv_dx.w, dv_dy.w, dv_dz.w,
                           dw_dx.w, dw_dy.w, dw_dz.w);

        um = uc; vm = vc; wm = wc;
        uc = up; vc = vp; wc = wp;
        oC += PLANE;
    }

    #pragma unroll
    for (int off = 32; off > 0; off >>= 1)
        vsum += __shfl_down(vsum, off, 64);

    __shared__ float wpart[4];
    if (lane == 0) wpart[tid >> 6] = vsum;
    __syncthreads();
    if (tid == 0) {
        const int blk = blockIdx.x + GT * (blockIdx.y + NCH * blockIdx.z);
        partial[blk] = (double)wpart[0] + (double)wpart[1]
                     + (double)wpart[2] + (double)wpart[3];
    }
}

__global__ __launch_bounds__(256)
void elastic_finalize(const double* __restrict__ partial, float* __restrict__ out) {
    const int t = threadIdx.x;
    double s = 0.0;
    for (int idx = t; idx < NBLK; idx += 256) s += partial[idx];

    #pragma unroll
    for (int off = 32; off > 0; off >>= 1)
        s += __shfl_down(s, off, 64);

    __shared__ double wpart[4];
    if ((t & 63) == 0) wpart[t >> 6] = s;
    __syncthreads();
    if (t == 0) {
        double tot = wpart[0] + wpart[1] + wpart[2] + wpart[3];
        out[0] = (float)(tot * (1.0 / 14155776.0));
    }
}

extern "C" void kernel_launch(void* const* d_in, const int* in_sizes, int n_in,
                              void* d_out, int out_size, void* d_ws, size_t ws_size,
                              hipStream_t stream) {
    const float* df = (const float*)d_in[0];
    double* partial = (double*)d_ws;   // NBLK doubles, plain stores (no init)
    float* out = (float*)d_out;

    dim3 grid(GT, NCH, 2);             // 2304 blocks = 9/CU -> 8 resident (32 waves/CU)
    elastic_main<<<grid, 256, 0, stream>>>(df, partial);
    elastic_finalize<<<1, 256, 0, stream>>>(partial, out);
}

// Round 8
// 241.935 us; speedup vs baseline: 2.1829x; 1.0116x over previous
//
#include <hip/hip_runtime.h>

#define DIM 192
#define PLANE (DIM * DIM)              // 36864 floats per x-plane
#define VOL (PLANE * DIM)              // 7077888 floats per field (fits int)
#define DCH 6                          // i-chunk depth
#define NCH (DIM / DCH)                // 32 chunks
#define GT 36                          // g-tiles per plane: 9216 float4 / 256
#define NBLK (GT * NCH * 2)            // 2304 blocks = 9 blocks/CU

typedef float v4 __attribute__((ext_vector_type(4)));

__device__ __forceinline__ float4 ldg4(const float* __restrict__ p, int off) {
    return *(const float4*)(p + off);
}

// robust(x)^2 building block: r = m*(|x| - 0.5*m), m = min(|x|, 0.01)
// (vectorized -> v_pk_* on CDNA4)
__device__ __forceinline__ v4 robust4(v4 x) {
    v4 ax = __builtin_elementwise_abs(x);
    v4 m  = __builtin_elementwise_min(ax, (v4)(0.01f));
    return m * (ax - 0.5f * m);
}

__device__ __forceinline__ v4 sub_scale4(float4 a, float4 b, float s) {
    v4 r;
    r.x = (a.x - b.x) * s; r.y = (a.y - b.y) * s;
    r.z = (a.z - b.z) * s; r.w = (a.w - b.w) * s;
    return r;
}

__device__ __forceinline__ v4 zgrad4(float4 c, float lf, float rt,
                                     bool leftEdge, bool rightEdge) {
    v4 g;
    g.x = leftEdge  ? (c.y - c.x) : 0.5f * (c.y - lf);
    g.y = 0.5f * (c.z - c.x);
    g.z = 0.5f * (c.w - c.y);
    g.w = rightEdge ? (c.w - c.z) : 0.5f * (rt - c.z);
    return g;
}

// R7 structure (rolled loop, 2304 blocks, 64 VGPR target) with all per-voxel
// math in ext-vector float4 -> packed dual-FP32 (v_pk_fma_f32 etc).
// Constant factors (0.5, 2.0, 0.1) are folded into the final combine.
__global__ __launch_bounds__(256, 4)
void elastic_main(const float* __restrict__ df, double* __restrict__ partial) {
    const int tid  = threadIdx.x;              // 0..255
    const int lane = tid & 63;
    const int g    = blockIdx.x * 256 + tid;   // float4 index in plane, 0..9215
    const int g4   = g * 4;                    // float offset in plane
    const int gmod = g % 48;                   // float4 index within row
    const int j    = g / 48;
    const int i0   = blockIdx.y * DCH;
    const int b    = blockIdx.z;

    const float* __restrict__ u = df + (size_t)(b * 3 + 0) * VOL;
    const float* __restrict__ v = df + (size_t)(b * 3 + 1) * VOL;
    const float* __restrict__ w = df + (size_t)(b * 3 + 2) * VOL;

    const bool leftEdge  = (gmod == 0);
    const bool rightEdge = (gmod == 47);

    const int jp = (j < DIM - 1) ? j + 1 : j;
    const int jm = (j > 0) ? j - 1 : j;
    const float sy = ((jp - jm) == 2) ? 0.5f : 1.0f;
    const int yOfsP = jp * DIM + gmod * 4;     // float offset within plane
    const int yOfsM = jm * DIM + gmod * 4;

    // z-halo: lane0 needs element g4-1 (its lf), lane63 needs g4+4 (its rt)
    const bool doHalo = (lane == 0) || (lane == 63);
    const int hOfs = (lane == 0) ? (leftEdge ? g4 : g4 - 1)
                                 : (rightEdge ? g4 : g4 + 4);

    // rotation registers: center rows of planes max(i-1,0), i
    float4 um, vm, wm, uc, vc, wc;
    {
        const int im1 = (i0 > 0) ? i0 - 1 : 0;
        um = ldg4(u, im1 * PLANE + g4); vm = ldg4(v, im1 * PLANE + g4);
        wm = ldg4(w, im1 * PLANE + g4);
        uc = ldg4(u, i0 * PLANE + g4);  vc = ldg4(v, i0 * PLANE + g4);
        wc = ldg4(w, i0 * PLANE + g4);
    }

    v4 accA = (v4)(0.f);   // rtr^2 + rxx^2 + ryy^2 + rzz^2   (weight 0.5)
    v4 accB = (v4)(0.f);   // rxy^2 + rxz^2 + ryz^2           (weight 1.0)
    v4 accC = (v4)(0.f);   // relu(-jac)                      (weight 0.1)
    int oC = i0 * PLANE;                       // plane-i base (float offset)

    for (int ii = 0; ii < DCH; ++ii) {
        const int i = i0 + ii;
        const int oP = oC + ((i < DIM - 1) ? PLANE : 0);   // clamped i+1 plane
        const float sx = (i > 0 && i < DIM - 1) ? 0.5f : 1.0f;

        const float4 up  = ldg4(u, oP + g4);
        const float4 vp  = ldg4(v, oP + g4);
        const float4 wp  = ldg4(w, oP + g4);
        const float4 uyp = ldg4(u, oC + yOfsP);
        const float4 uym = ldg4(u, oC + yOfsM);
        const float4 vyp = ldg4(v, oC + yOfsP);
        const float4 vym = ldg4(v, oC + yOfsM);
        const float4 wyp = ldg4(w, oC + yOfsP);
        const float4 wym = ldg4(w, oC + yOfsM);

        float hu = 0.f, hv = 0.f, hw = 0.f;
        if (doHalo) {                           // 1 predicated dword load/field
            hu = u[oC + hOfs]; hv = v[oC + hOfs]; hw = w[oC + hOfs];
        }

        float ulf = __shfl_up(uc.w, 1);
        float vlf = __shfl_up(vc.w, 1);
        float wlf = __shfl_up(wc.w, 1);
        float urt = __shfl_down(uc.x, 1);
        float vrt = __shfl_down(vc.x, 1);
        float wrt = __shfl_down(wc.x, 1);
        if (lane == 0)  { ulf = hu; vlf = hv; wlf = hw; }
        if (lane == 63) { urt = hu; vrt = hv; wrt = hw; }

        const v4 du_dz = zgrad4(uc, ulf, urt, leftEdge, rightEdge);
        const v4 dv_dz = zgrad4(vc, vlf, vrt, leftEdge, rightEdge);
        const v4 dw_dz = zgrad4(wc, wlf, wrt, leftEdge, rightEdge);

        const v4 du_dx = sub_scale4(up, um, sx);
        const v4 dv_dx = sub_scale4(vp, vm, sx);
        const v4 dw_dx = sub_scale4(wp, wm, sx);
        const v4 du_dy = sub_scale4(uyp, uym, sy);
        const v4 dv_dy = sub_scale4(vyp, vym, sy);
        const v4 dw_dy = sub_scale4(wyp, wym, sy);

        // ---- packed per-voxel math over 4 voxels ----
        const v4 E_xy = 0.5f * (du_dy + dv_dx);
        const v4 E_xz = 0.5f * (du_dz + dw_dx);
        const v4 E_yz = 0.5f * (dv_dz + dw_dy);
        const v4 tr   = du_dx + dv_dy + dw_dz;

        const v4 rtr = robust4(tr);
        const v4 rxx = robust4(du_dx), ryy = robust4(dv_dy), rzz = robust4(dw_dz);
        const v4 rxy = robust4(E_xy),  rxz = robust4(E_xz),  ryz = robust4(E_yz);

        accA += rtr * rtr + rxx * rxx + ryy * ryy + rzz * rzz;
        accB += rxy * rxy + rxz * rxz + ryz * ryz;

        // Replicate the reference expression EXACTLY (not the true determinant).
        const v4 a11 = 1.0f + du_dx;
        const v4 a22 = 1.0f + dv_dy;
        const v4 a33 = 1.0f + dw_dz;
        const v4 a31 = 1.0f + dw_dx;   // note: reference uses (1+dw_dx) here
        const v4 jac = a11 * (a22 * a33 - dv_dz * dw_dy)
                     - du_dy * (dv_dx * a33 - dv_dz * a31)
                     + du_dz * (dv_dx * dw_dy - a22 * a31);
        accC += __builtin_elementwise_max(-jac, (v4)(0.f));

        // rotate planes
        um = uc; vm = vc; wm = wc;
        uc = up; vc = vp; wc = wp;
        oC += PLANE;
    }

    // final combine with folded weights
    const v4 tot4 = 0.5f * accA + accB + 0.1f * accC;
    float vsum = tot4.x + tot4.y + tot4.z + tot4.w;

    #pragma unroll
    for (int off = 32; off > 0; off >>= 1)
        vsum += __shfl_down(vsum, off, 64);

    __shared__ float wpart[4];
    if (lane == 0) wpart[tid >> 6] = vsum;
    __syncthreads();
    if (tid == 0) {
        const int blk = blockIdx.x + GT * (blockIdx.y + NCH * blockIdx.z);
        partial[blk] = (double)wpart[0] + (double)wpart[1]
                     + (double)wpart[2] + (double)wpart[3];
    }
}

__global__ __launch_bounds__(256)
void elastic_finalize(const double* __restrict__ partial, float* __restrict__ out) {
    const int t = threadIdx.x;
    double s = 0.0;
    for (int idx = t; idx < NBLK; idx += 256) s += partial[idx];

    #pragma unroll
    for (int off = 32; off > 0; off >>= 1)
        s += __shfl_down(s, off, 64);

    __shared__ double wpart[4];
    if ((t & 63) == 0) wpart[t >> 6] = s;
    __syncthreads();
    if (t == 0) {
        double tot = wpart[0] + wpart[1] + wpart[2] + wpart[3];
        out[0] = (float)(tot * (1.0 / 14155776.0));
    }
}

extern "C" void kernel_launch(void* const* d_in, const int* in_sizes, int n_in,
                              void* d_out, int out_size, void* d_ws, size_t ws_size,
                              hipStream_t stream) {
    const float* df = (const float*)d_in[0];
    double* partial = (double*)d_ws;   // NBLK doubles, plain stores (no init)
    float* out = (float*)d_out;

    dim3 grid(GT, NCH, 2);             // 2304 blocks = 9/CU -> 8 resident (32 waves/CU)
    elastic_main<<<grid, 256, 0, stream>>>(df, partial);
    elastic_finalize<<<1, 256, 0, stream>>>(partial, out);
}